// Round 12
// baseline (490.234 us; speedup 1.0000x reference)
//
#include <hip/hip_runtime.h>
#include <hip/hip_bf16.h>
#include <cstddef>

#define N_NODES 20000
#define N_EDGES 320000
#define XDIM 128
#define H 256
#define LAYERS 4
#define G_GRAPHS 128
#define C_OUT 10
#define EPS_BN 1e-5f
#define NSLOT 64          // stats partial slots
#define NB 8              // nodes per block in agg

typedef __attribute__((ext_vector_type(8))) short short8;
typedef __attribute__((ext_vector_type(4))) float f32x4;
typedef __attribute__((address_space(3))) unsigned int lds_u32;
typedef const __attribute__((address_space(1))) unsigned int glob_u32;

// ---------------- degree histogram (by dst) ----------------
__global__ void hist_kernel(const int* __restrict__ dst, int* __restrict__ cnt, int E) {
    int e = blockIdx.x * blockDim.x + threadIdx.x;
    if (e < E) atomicAdd(&cnt[dst[e]], 1);
}

// ---------------- exclusive scan of cnt -> rowstart[N+1], fused dinv ----------------
__global__ void scan_kernel(const int* __restrict__ cnt, int* __restrict__ rowstart,
                            float* __restrict__ dinv, int N) {
    __shared__ int partial[1024];
    int tid = threadIdx.x;
    int chunk = (N + 1023) / 1024;
    int start = tid * chunk;
    int lsum = 0;
    for (int i = 0; i < chunk; ++i) {
        int idx = start + i;
        if (idx < N) {
            int c = cnt[idx];
            dinv[idx] = 1.0f / sqrtf((float)c + 1.0f);
            lsum += c;
        }
    }
    partial[tid] = lsum;
    __syncthreads();
    for (int off = 1; off < 1024; off <<= 1) {
        int v = (tid >= off) ? partial[tid - off] : 0;
        __syncthreads();
        partial[tid] += v;
        __syncthreads();
    }
    int run = (tid == 0) ? 0 : partial[tid - 1];
    for (int i = 0; i < chunk; ++i) {
        int idx = start + i;
        if (idx < N) { rowstart[idx] = run; run += cnt[idx]; }
    }
    if (tid == 1023) rowstart[N] = partial[1023];
}

// ---------------- CSR fill ----------------
__global__ void fill_kernel(const int* __restrict__ src, const int* __restrict__ dst,
                            const int* __restrict__ rowstart, int* __restrict__ cursor,
                            const float* __restrict__ dinv,
                            int* __restrict__ csr_src, float* __restrict__ csr_w, int E) {
    int e = blockIdx.x * blockDim.x + threadIdx.x;
    if (e < E) {
        int s = src[e], d = dst[e];
        int pos = rowstart[d] + atomicAdd(&cursor[d], 1);
        csr_src[pos] = s;
        csr_w[pos] = dinv[s] * dinv[d];
    }
}

// ---------------- fused prep: cast x -> bf16, transpose+cast encW & convW ----------------
__global__ void prep_kernel(const float* __restrict__ x, const float* __restrict__ encW,
                            const float* __restrict__ convW,
                            __hip_bfloat16* __restrict__ xbf,
                            __hip_bfloat16* __restrict__ encWT,
                            __hip_bfloat16* __restrict__ convWT) {
    int i = blockIdx.x * blockDim.x + threadIdx.x;
    const int nx = N_NODES * XDIM;
    const int ne = XDIM * H;
    const int nc = LAYERS * H * H;
    if (i < nx) {
        xbf[i] = __float2bfloat16(x[i]);
    } else if (i < nx + ne) {
        int j = i - nx;
        int r = j / H, c = j - r * H;
        encWT[c * XDIM + r] = __float2bfloat16(encW[j]);
    } else if (i < nx + ne + nc) {
        int j = i - nx - ne;
        int l = j / (H * H), rem = j - l * (H * H);
        int r = rem / H, c = rem - r * H;
        convWT[(size_t)l * H * H + c * H + r] = __float2bfloat16(convW[j]);
    }
}

__device__ __forceinline__ short bf16bits(float x) {
    __hip_bfloat16 b = __float2bfloat16(x);
    return *(short*)&b;
}

// ---------------- bf16 MFMA GEMM v2: barrier-free K-loop -----------------------
// 64x64 tile, 4 waves of 32x32. FULL B panel (64 cols x K) staged to LDS via
// async global_load_lds (32 KB @ K=256), ONE barrier total. A fragments are
// loaded DIRECTLY global->VGPR (16x16x32 A-frag = contiguous 16B/lane:
// A[row][k0+quad*8]) - no LDS round-trip, no K-loop barrier, waves free-run.
// Plain: all NK*2 A-frags preloaded (max MLP). FUSE_BN: depth-1 register
// pipeline (load fp32 k+1 while converting/MFMA k); BN math bit-identical.
template <int K, bool FUSE_BN>
__global__ __launch_bounds__(256) void gemm_bf16_kernel(
    const void* __restrict__ Ain,           // [M,K] bf16 (plain) or fp32 (FUSE_BN)
    const __hip_bfloat16* __restrict__ BT,  // [Nn,K] row-major (B transposed)
    const float* __restrict__ bias,         // [Nn] or nullptr
    const float* __restrict__ spart,        // [NSLOT][2H] stats partials (FUSE_BN)
    const float* __restrict__ gamma,        // [H] (FUSE_BN)
    const float* __restrict__ beta,         // [H] (FUSE_BN)
    __hip_bfloat16* __restrict__ Cbf,       // [M,Nn]
    int M, int Nn) {
    constexpr int NK = K / 32;
    __shared__ short Bs[NK][64 * 32];   // 32 KB @ K=256, 16 KB @ K=128
    __shared__ float scs[H];
    __shared__ float shs[H];
    const short* Ash = (const short*)Ain;
    const float* Af = (const float*)Ain;
    const short* Bsh = (const short*)BT;
    int tid = threadIdx.x;
    int lane = tid & 63;
    int wave = tid >> 6;
    int quad = lane >> 4;
    int lr = lane & 15;
    int wm = (wave & 1) * 32;
    int wn = (wave >> 1) * 32;
    int Mblk = blockIdx.x * 64;
    int Nblk = blockIdx.y * 64;

    // stage ENTIRE B panel: per chunk, 256 threads x 16B = 4 KB (64 rows x 32 k)
    int srow = tid >> 2, sqs = tid & 3;
    int sqg = sqs ^ ((srow >> 1) & 3);
    int brow = Nblk + srow;   // Nn is a multiple of 64
#pragma unroll
    for (int kc = 0; kc < NK; ++kc) {
        __builtin_amdgcn_global_load_lds(
            (glob_u32*)(Bsh + (size_t)brow * K + kc * 32 + sqg * 8),
            (lds_u32*)&Bs[kc][0] + wave * 256, 16, 0, 0);
    }

    if (FUSE_BN) {
        // per-block BN params (identical arithmetic to R8's make_bnparams)
        int c = tid;
        float s = 0.f, s2 = 0.f;
#pragma unroll 8
        for (int i = 0; i < NSLOT; ++i) {
            s  += spart[(size_t)i * (2 * H) + c];
            s2 += spart[(size_t)i * (2 * H) + H + c];
        }
        float invN = 1.0f / (float)N_NODES;
        float mean = s * invN;
        float var = s2 * invN - mean * mean;
        float kk = gamma[c] / sqrtf(var + EPS_BN);
        scs[c] = kk;
        shs[c] = beta[c] - mean * kk;
    }
    __syncthreads();   // the ONLY block-wide barrier: B panel + scs/shs ready

    // A rows for this lane (clamped; OOB rows write-guarded in epilogue)
    int grow[2];
#pragma unroll
    for (int mi = 0; mi < 2; ++mi) {
        int r = Mblk + wm + mi * 16 + lr;
        grow[mi] = r < M ? r : M - 1;
    }

    f32x4 acc[2][2];
#pragma unroll
    for (int i = 0; i < 2; ++i)
#pragma unroll
        for (int j = 0; j < 2; ++j) acc[i][j] = (f32x4){0.f, 0.f, 0.f, 0.f};

    if (FUSE_BN) {
        // depth-1 pipeline: fp32 raw of k+1 in flight while k converts+MFMAs
        float4 c0a, c0b, c1a, c1b;   // raw A: [mi][lo/hi]
        {
            int kc = 0 * 32 + quad * 8;
            c0a = *(const float4*)(Af + (size_t)grow[0] * K + kc);
            c0b = *(const float4*)(Af + (size_t)grow[0] * K + kc + 4);
            c1a = *(const float4*)(Af + (size_t)grow[1] * K + kc);
            c1b = *(const float4*)(Af + (size_t)grow[1] * K + kc + 4);
        }
#pragma unroll
        for (int k = 0; k < NK; ++k) {
            float4 n0a, n0b, n1a, n1b;
            if (k + 1 < NK) {
                int kc = (k + 1) * 32 + quad * 8;
                n0a = *(const float4*)(Af + (size_t)grow[0] * K + kc);
                n0b = *(const float4*)(Af + (size_t)grow[0] * K + kc + 4);
                n1a = *(const float4*)(Af + (size_t)grow[1] * K + kc);
                n1b = *(const float4*)(Af + (size_t)grow[1] * K + kc + 4);
            }
            int kc = k * 32 + quad * 8;
            float4 s0 = *(const float4*)&scs[kc];
            float4 s1 = *(const float4*)&scs[kc + 4];
            float4 h0 = *(const float4*)&shs[kc];
            float4 h1 = *(const float4*)&shs[kc + 4];
            short8 aqk[2];
            {
                short8 pk;
                pk[0] = bf16bits(fmaxf(c0a.x * s0.x + h0.x, 0.f));
                pk[1] = bf16bits(fmaxf(c0a.y * s0.y + h0.y, 0.f));
                pk[2] = bf16bits(fmaxf(c0a.z * s0.z + h0.z, 0.f));
                pk[3] = bf16bits(fmaxf(c0a.w * s0.w + h0.w, 0.f));
                pk[4] = bf16bits(fmaxf(c0b.x * s1.x + h1.x, 0.f));
                pk[5] = bf16bits(fmaxf(c0b.y * s1.y + h1.y, 0.f));
                pk[6] = bf16bits(fmaxf(c0b.z * s1.z + h1.z, 0.f));
                pk[7] = bf16bits(fmaxf(c0b.w * s1.w + h1.w, 0.f));
                aqk[0] = pk;
                pk[0] = bf16bits(fmaxf(c1a.x * s0.x + h0.x, 0.f));
                pk[1] = bf16bits(fmaxf(c1a.y * s0.y + h0.y, 0.f));
                pk[2] = bf16bits(fmaxf(c1a.z * s0.z + h0.z, 0.f));
                pk[3] = bf16bits(fmaxf(c1a.w * s0.w + h0.w, 0.f));
                pk[4] = bf16bits(fmaxf(c1b.x * s1.x + h1.x, 0.f));
                pk[5] = bf16bits(fmaxf(c1b.y * s1.y + h1.y, 0.f));
                pk[6] = bf16bits(fmaxf(c1b.z * s1.z + h1.z, 0.f));
                pk[7] = bf16bits(fmaxf(c1b.w * s1.w + h1.w, 0.f));
                aqk[1] = pk;
            }
            short8 bfr[2];
#pragma unroll
            for (int ni = 0; ni < 2; ++ni) {
                int r = wn + ni * 16 + lr;
                bfr[ni] = *(const short8*)&Bs[k][r * 32 + (quad ^ ((r >> 1) & 3)) * 8];
            }
#pragma unroll
            for (int mi = 0; mi < 2; ++mi)
#pragma unroll
                for (int ni = 0; ni < 2; ++ni)
                    acc[mi][ni] = __builtin_amdgcn_mfma_f32_16x16x32_bf16(aqk[mi], bfr[ni], acc[mi][ni], 0, 0, 0);
            c0a = n0a; c0b = n0b; c1a = n1a; c1b = n1b;
        }
    } else {
        // preload ALL A fragments: NK x 2 independent 16B loads in flight
        short8 aq[NK][2];
#pragma unroll
        for (int k = 0; k < NK; ++k)
#pragma unroll
            for (int mi = 0; mi < 2; ++mi)
                aq[k][mi] = *(const short8*)(Ash + (size_t)grow[mi] * K + k * 32 + quad * 8);
#pragma unroll
        for (int k = 0; k < NK; ++k) {
            short8 bfr[2];
#pragma unroll
            for (int ni = 0; ni < 2; ++ni) {
                int r = wn + ni * 16 + lr;
                bfr[ni] = *(const short8*)&Bs[k][r * 32 + (quad ^ ((r >> 1) & 3)) * 8];
            }
#pragma unroll
            for (int mi = 0; mi < 2; ++mi)
#pragma unroll
                for (int ni = 0; ni < 2; ++ni)
                    acc[mi][ni] = __builtin_amdgcn_mfma_f32_16x16x32_bf16(aq[k][mi], bfr[ni], acc[mi][ni], 0, 0, 0);
        }
    }

    // epilogue
#pragma unroll
    for (int mi = 0; mi < 2; ++mi) {
#pragma unroll
        for (int r = 0; r < 4; ++r) {
            int m = Mblk + wm + mi * 16 + quad * 4 + r;
            if (m < M) {
#pragma unroll
                for (int ni = 0; ni < 2; ++ni) {
                    int n = Nblk + wn + ni * 16 + lr;
                    float v = acc[mi][ni][r];
                    if (bias) v += bias[n];
                    Cbf[(size_t)m * Nn + n] = __float2bfloat16(v);
                }
            }
        }
    }
}

// ---------------- aggregation v3 + fused BN-stats (SETTLED structure) -------------
// R4/R10: issue/latency-bound, not traffic-bound - full 512B row per load,
// single pass, 16 streams/block. R11: barriers hidden by TLP.
__global__ __launch_bounds__(256) void agg_kernel(const __hip_bfloat16* __restrict__ t,
                           const int* __restrict__ rowstart,
                           const int* __restrict__ csr_src,
                           const float* __restrict__ csr_w,
                           const float* __restrict__ dinv,
                           const float* __restrict__ convB,
                           float* __restrict__ out,
                           float* __restrict__ spart,  // [NSLOT][2*H]
                           int N) {
    __shared__ float red[2][4][256];  // double-buffered
    int tid = threadIdx.x;
    int wave = tid >> 6;
    int lane = tid & 63;
    int sub = lane >> 5;          // half-wave
    int hl = lane & 31;
    int stream = wave * 2 + sub;  // 0..7
    int c0 = hl * 8;              // gather channel base (8 channels/lane)
    const ushort* tp = (const ushort*)t;
    float sv = 0.f, sq = 0.f;
    int n0 = blockIdx.x * NB;
#pragma unroll 1
    for (int it = 0; it < NB; ++it) {
        int n = n0 + it;
        int s = rowstart[n], e = rowstart[n + 1];
        float a[8] = {};
#pragma unroll 1
        for (int j0 = s; j0 < e; j0 += 16) {
#pragma unroll
            for (int u = 0; u < 2; ++u) {
                int j = j0 + u * 8 + stream;
                int idx = n; float w = 0.f;
                if (j < e) { idx = csr_src[j]; w = csr_w[j]; }
                uint4 v = *(const uint4*)(tp + (size_t)idx * H + c0);
                a[0] += __uint_as_float(v.x << 16) * w;
                a[1] += __uint_as_float(v.x & 0xffff0000u) * w;
                a[2] += __uint_as_float(v.y << 16) * w;
                a[3] += __uint_as_float(v.y & 0xffff0000u) * w;
                a[4] += __uint_as_float(v.z << 16) * w;
                a[5] += __uint_as_float(v.z & 0xffff0000u) * w;
                a[6] += __uint_as_float(v.w << 16) * w;
                a[7] += __uint_as_float(v.w & 0xffff0000u) * w;
            }
        }
#pragma unroll
        for (int k = 0; k < 8; ++k) a[k] += __shfl_xor(a[k], 32);
        int buf = it & 1;
        if (sub == 0) {
            *(float4*)&red[buf][wave][c0] = make_float4(a[0], a[1], a[2], a[3]);
            *(float4*)&red[buf][wave][c0 + 4] = make_float4(a[4], a[5], a[6], a[7]);
        }
        __syncthreads();
        int c = tid;  // channel
        float val = red[buf][0][c] + red[buf][1][c] + red[buf][2][c] + red[buf][3][c];
        float dn = dinv[n];
        val += __bfloat162float(t[(size_t)n * H + c]) * (dn * dn) + convB[c];
        out[(size_t)n * H + c] = val;
        sv += val; sq += val * val;
    }
    float* sp = spart + (size_t)(blockIdx.x & (NSLOT - 1)) * (2 * H);
    atomicAdd(&sp[tid], sv);
    atomicAdd(&sp[H + tid], sq);
}

// ---------------- global mean pool, fused per-block BN params + BN+ReLU ----------
__global__ __launch_bounds__(256) void pool_kernel(const float* __restrict__ t2,
                            const int* __restrict__ batch,
                            const float* __restrict__ spart,
                            const float* __restrict__ gamma,
                            const float* __restrict__ beta,
                            float* __restrict__ g, int N) {
    __shared__ float4 red[4][64];
    __shared__ float scs[H];
    __shared__ float shs[H];
    {
        int c = threadIdx.x;
        float s = 0.f, s2 = 0.f;
#pragma unroll 8
        for (int i = 0; i < NSLOT; ++i) {
            s  += spart[(size_t)i * (2 * H) + c];
            s2 += spart[(size_t)i * (2 * H) + H + c];
        }
        float invN = 1.0f / (float)N_NODES;
        float mean = s * invN;
        float var = s2 * invN - mean * mean;
        float kk = gamma[c] / sqrtf(var + EPS_BN);
        scs[c] = kk;
        shs[c] = beta[c] - mean * kk;
    }
    __syncthreads();
    int gid = blockIdx.x;
    int lo = 0, hi = N;
    while (lo < hi) { int mid = (lo + hi) >> 1; if (batch[mid] < gid) lo = mid + 1; else hi = mid; }
    int s = lo;
    lo = s; hi = N;
    while (lo < hi) { int mid = (lo + hi) >> 1; if (batch[mid] < gid + 1) lo = mid + 1; else hi = mid; }
    int e = lo;
    int wave = threadIdx.x >> 6;
    int lane = threadIdx.x & 63;
    float4 scv = *(const float4*)&scs[lane * 4];
    float4 shv = *(const float4*)&shs[lane * 4];
    float a0 = 0.f, a1 = 0.f, a2 = 0.f, a3 = 0.f;
    for (int r = s + wave; r < e; r += 4) {
        float4 v = *(const float4*)(t2 + (size_t)r * H + lane * 4);
        a0 += __bfloat162float(__float2bfloat16(fmaxf(v.x * scv.x + shv.x, 0.f)));
        a1 += __bfloat162float(__float2bfloat16(fmaxf(v.y * scv.y + shv.y, 0.f)));
        a2 += __bfloat162float(__float2bfloat16(fmaxf(v.z * scv.z + shv.z, 0.f)));
        a3 += __bfloat162float(__float2bfloat16(fmaxf(v.w * scv.w + shv.w, 0.f)));
    }
    red[wave][lane] = make_float4(a0, a1, a2, a3);
    __syncthreads();
    int c = threadIdx.x;
    const float* rf = (const float*)red;
    float sum = rf[c] + rf[256 + c] + rf[512 + c] + rf[768 + c];
    g[(size_t)gid * H + c] = sum / fmaxf((float)(e - s), 1.0f);
}

// ---------------- FC with compile-time K/NN ----------------
template <int K, int NN>
__global__ __launch_bounds__(256) void fc_lds_kernel(const float* __restrict__ in,
                                                     const float* __restrict__ W,
                                                     const float* __restrict__ b,
                                                     float* __restrict__ out) {
    __shared__ float row[K];
    int g = blockIdx.x;
    for (int k = threadIdx.x; k < K; k += 256) row[k] = in[(size_t)g * K + k];
    __syncthreads();
    int hc = threadIdx.x;
    if (hc < NN) {
        float acc = b[hc];
#pragma unroll
        for (int k = 0; k < K; ++k) acc += row[k] * W[k * NN + hc];
        out[(size_t)g * NN + hc] = acc;
    }
}

// ---------------- final FC ----------------
__global__ void fc_out_kernel(const float* __restrict__ in, const float* __restrict__ W,
                              const float* __restrict__ b, float* __restrict__ out) {
    int t = blockIdx.x * blockDim.x + threadIdx.x;
    if (t >= G_GRAPHS * C_OUT) return;
    int g = t / C_OUT, c = t % C_OUT;
    float acc = b[c];
#pragma unroll 16
    for (int k = 0; k < H; ++k) acc += in[(size_t)g * H + k] * W[k * C_OUT + c];
    out[t] = acc;
}

// ---------------- BN over small [G,H] ----------------
__global__ void bn_head_kernel(const float* __restrict__ in, const float* __restrict__ gamma,
                               const float* __restrict__ beta, float* __restrict__ out,
                               int Grows, int relu) {
    int c = blockIdx.x;
    int r = threadIdx.x;
    __shared__ float red[G_GRAPHS];
    float v = in[r * H + c];
    red[r] = v;
    __syncthreads();
    for (int off = G_GRAPHS / 2; off > 0; off >>= 1) {
        if (r < off) red[r] += red[r + off];
        __syncthreads();
    }
    float mean = red[0] / (float)Grows;
    __syncthreads();
    float d = v - mean;
    red[r] = d * d;
    __syncthreads();
    for (int off = G_GRAPHS / 2; off > 0; off >>= 1) {
        if (r < off) red[r] += red[r + off];
        __syncthreads();
    }
    float var = red[0] / (float)Grows;
    float y = gamma[c] * d / sqrtf(var + EPS_BN) + beta[c];
    if (relu) y = fmaxf(y, 0.f);
    out[r * H + c] = y;
}

extern "C" void kernel_launch(void* const* d_in, const int* in_sizes, int n_in,
                              void* d_out, int out_size, void* d_ws, size_t ws_size,
                              hipStream_t stream) {
    const float* x     = (const float*)d_in[0];
    const int*   edge  = (const int*)d_in[1];
    const int*   batch = (const int*)d_in[2];
    const float* encW  = (const float*)d_in[3];
    const float* encB  = (const float*)d_in[4];
    const float* convW = (const float*)d_in[5];
    const float* convB = (const float*)d_in[6];
    const float* bnG   = (const float*)d_in[7];
    const float* bnB   = (const float*)d_in[8];
    const float* fcW1  = (const float*)d_in[9];
    const float* fcB1  = (const float*)d_in[10];
    const float* fcG1  = (const float*)d_in[11];
    const float* fcBe1 = (const float*)d_in[12];
    const float* fcW2  = (const float*)d_in[13];
    const float* fcB2  = (const float*)d_in[14];
    const float* fcG2  = (const float*)d_in[15];
    const float* fcBe2 = (const float*)d_in[16];
    const float* fcW3  = (const float*)d_in[17];
    const float* fcB3  = (const float*)d_in[18];
    float* out = (float*)d_out;

    const int* srcIdx = edge;
    const int* dstIdx = edge + N_EDGES;

    char* base = (char*)d_ws;
    size_t off = 0;
    auto alloc = [&](size_t bytes) -> void* {
        void* p = base + off;
        off = (off + bytes + 255) & ~(size_t)255;
        return p;
    };
    int*   cnt      = (int*)alloc(N_NODES * 4);
    int*   cursor   = (int*)alloc(N_NODES * 4);
    int*   rowstart = (int*)alloc((N_NODES + 1) * 4);
    float* dinv     = (float*)alloc(N_NODES * 4);
    int*   csr_src  = (int*)alloc(N_EDGES * 4);
    float* csr_w    = (float*)alloc(N_EDGES * 4);
    float* spart    = (float*)alloc((size_t)LAYERS * NSLOT * 2 * H * 4);
    __hip_bfloat16* xbf    = (__hip_bfloat16*)alloc((size_t)N_NODES * XDIM * 2);
    __hip_bfloat16* encWT  = (__hip_bfloat16*)alloc((size_t)H * XDIM * 2);
    __hip_bfloat16* convWT = (__hip_bfloat16*)alloc((size_t)LAYERS * H * H * 2);
    __hip_bfloat16* hbf    = (__hip_bfloat16*)alloc((size_t)N_NODES * H * 2);
    __hip_bfloat16* tbf    = (__hip_bfloat16*)alloc((size_t)N_NODES * H * 2);
    float* t2buf = (float*)alloc((size_t)N_NODES * H * 4);
    float* gpool = (float*)alloc(G_GRAPHS * H * 4);
    float* m1    = (float*)alloc(G_GRAPHS * H * 4);
    float* m2    = (float*)alloc(G_GRAPHS * H * 4);

    // cnt+cursor are contiguous in ws -> one memset
    hipMemsetAsync(cnt, 0, (size_t)((char*)rowstart - (char*)cnt), stream);
    hipMemsetAsync(spart, 0, (size_t)LAYERS * NSLOT * 2 * H * 4, stream);

    // CSR build
    hist_kernel<<<(N_EDGES + 255) / 256, 256, 0, stream>>>(dstIdx, cnt, N_EDGES);
    scan_kernel<<<1, 1024, 0, stream>>>(cnt, rowstart, dinv, N_NODES);
    fill_kernel<<<(N_EDGES + 255) / 256, 256, 0, stream>>>(srcIdx, dstIdx, rowstart, cursor,
                                                           dinv, csr_src, csr_w, N_EDGES);

    // fused prep (cast + transposes)
    {
        int total = N_NODES * XDIM + XDIM * H + LAYERS * H * H;
        prep_kernel<<<(total + 255) / 256, 256, 0, stream>>>(x, encW, convW, xbf, encWT, convWT);
    }

    // encoder: h = x @ encW + encB
    dim3 gridG((N_NODES + 63) / 64, H / 64);
    gemm_bf16_kernel<XDIM, false><<<gridG, 256, 0, stream>>>(
        xbf, encWT, encB, nullptr, nullptr, nullptr, hbf, N_NODES, H);

    // conv layers: gemm (BN of prev layer fused into A path for l>=1), agg(+stats)
    for (int l = 0; l < LAYERS; ++l) {
        float* spartL = spart + (size_t)l * NSLOT * 2 * H;
        if (l == 0) {
            gemm_bf16_kernel<H, false><<<gridG, 256, 0, stream>>>(
                hbf, convWT + (size_t)l * H * H, nullptr, nullptr, nullptr, nullptr,
                tbf, N_NODES, H);
        } else {
            float* spartP = spart + (size_t)(l - 1) * NSLOT * 2 * H;
            gemm_bf16_kernel<H, true><<<gridG, 256, 0, stream>>>(
                t2buf, convWT + (size_t)l * H * H, nullptr,
                spartP, bnG + (size_t)(l - 1) * H, bnB + (size_t)(l - 1) * H,
                tbf, N_NODES, H);
        }
        agg_kernel<<<N_NODES / NB, 256, 0, stream>>>(tbf, rowstart, csr_src, csr_w, dinv,
                                                     convB + l * H, t2buf, spartL, N_NODES);
    }

    // pool (BN+ReLU of layer 3 fused, params computed per-block)
    pool_kernel<<<G_GRAPHS, 256, 0, stream>>>(
        t2buf, batch, spart + (size_t)(LAYERS - 1) * NSLOT * 2 * H,
        bnG + (size_t)(LAYERS - 1) * H, bnB + (size_t)(LAYERS - 1) * H, gpool, N_NODES);

    // head
    fc_lds_kernel<H, H><<<G_GRAPHS, 256, 0, stream>>>(gpool, fcW1, fcB1, m1);
    bn_head_kernel<<<H, G_GRAPHS, 0, stream>>>(m1, fcG1, fcBe1, m1, G_GRAPHS, 1);
    fc_lds_kernel<H, H><<<G_GRAPHS, 256, 0, stream>>>(m1, fcW2, fcB2, m2);
    bn_head_kernel<<<H, G_GRAPHS, 0, stream>>>(m2, fcG2, fcBe2, m2, G_GRAPHS, 0);
    fc_out_kernel<<<(G_GRAPHS * C_OUT + 255) / 256, 256, 0, stream>>>(m2, fcW3, fcB3, out);
}

// Round 13
// 445.914 us; speedup vs baseline: 1.0994x; 1.0994x over previous
//
#include <hip/hip_runtime.h>
#include <hip/hip_bf16.h>
#include <cstddef>

#define N_NODES 20000
#define N_EDGES 320000
#define XDIM 128
#define H 256
#define LAYERS 4
#define G_GRAPHS 128
#define C_OUT 10
#define EPS_BN 1e-5f
#define NSLOT 64          // stats partial slots
#define NB 8              // nodes per block in agg

typedef __attribute__((ext_vector_type(8))) short short8;
typedef __attribute__((ext_vector_type(4))) float f32x4;
typedef __attribute__((address_space(3))) unsigned int lds_u32;
typedef const __attribute__((address_space(1))) unsigned int glob_u32;

// ---------------- degree histogram (by dst) ----------------
__global__ void hist_kernel(const int* __restrict__ dst, int* __restrict__ cnt, int E) {
    int e = blockIdx.x * blockDim.x + threadIdx.x;
    if (e < E) atomicAdd(&cnt[dst[e]], 1);
}

// ---------------- exclusive scan of cnt -> rowstart[N+1], fused dinv ----------------
__global__ void scan_kernel(const int* __restrict__ cnt, int* __restrict__ rowstart,
                            float* __restrict__ dinv, int N) {
    __shared__ int partial[1024];
    int tid = threadIdx.x;
    int chunk = (N + 1023) / 1024;
    int start = tid * chunk;
    int lsum = 0;
    for (int i = 0; i < chunk; ++i) {
        int idx = start + i;
        if (idx < N) {
            int c = cnt[idx];
            dinv[idx] = 1.0f / sqrtf((float)c + 1.0f);
            lsum += c;
        }
    }
    partial[tid] = lsum;
    __syncthreads();
    for (int off = 1; off < 1024; off <<= 1) {
        int v = (tid >= off) ? partial[tid - off] : 0;
        __syncthreads();
        partial[tid] += v;
        __syncthreads();
    }
    int run = (tid == 0) ? 0 : partial[tid - 1];
    for (int i = 0; i < chunk; ++i) {
        int idx = start + i;
        if (idx < N) { rowstart[idx] = run; run += cnt[idx]; }
    }
    if (tid == 1023) rowstart[N] = partial[1023];
}

// ---------------- CSR fill ----------------
__global__ void fill_kernel(const int* __restrict__ src, const int* __restrict__ dst,
                            const int* __restrict__ rowstart, int* __restrict__ cursor,
                            const float* __restrict__ dinv,
                            int* __restrict__ csr_src, float* __restrict__ csr_w, int E) {
    int e = blockIdx.x * blockDim.x + threadIdx.x;
    if (e < E) {
        int s = src[e], d = dst[e];
        int pos = rowstart[d] + atomicAdd(&cursor[d], 1);
        csr_src[pos] = s;
        csr_w[pos] = dinv[s] * dinv[d];
    }
}

// ---------------- fused prep: cast x -> bf16, transpose+cast encW & convW ----------------
__global__ void prep_kernel(const float* __restrict__ x, const float* __restrict__ encW,
                            const float* __restrict__ convW,
                            __hip_bfloat16* __restrict__ xbf,
                            __hip_bfloat16* __restrict__ encWT,
                            __hip_bfloat16* __restrict__ convWT) {
    int i = blockIdx.x * blockDim.x + threadIdx.x;
    const int nx = N_NODES * XDIM;
    const int ne = XDIM * H;
    const int nc = LAYERS * H * H;
    if (i < nx) {
        xbf[i] = __float2bfloat16(x[i]);
    } else if (i < nx + ne) {
        int j = i - nx;
        int r = j / H, c = j - r * H;
        encWT[c * XDIM + r] = __float2bfloat16(encW[j]);
    } else if (i < nx + ne + nc) {
        int j = i - nx - ne;
        int l = j / (H * H), rem = j - l * (H * H);
        int r = rem / H, c = rem - r * H;
        convWT[(size_t)l * H * H + c * H + r] = __float2bfloat16(convW[j]);
    }
}

__device__ __forceinline__ short bf16bits(float x) {
    __hip_bfloat16 b = __float2bfloat16(x);
    return *(short*)&b;
}

// ---------------- bf16 MFMA GEMM (R8/R11 config: 64x128 tile, dbuf, async LDS) ----
// SETTLED (R9 dbuf-neutral, R12 barrier-free regressed): this 2-barrier 64x128
// shape with global_load_lds staging is the empirical optimum of all variants.
template <int K, bool FUSE_BN>
__global__ __launch_bounds__(256) void gemm_bf16_kernel(
    const void* __restrict__ Ain,           // [M,K] bf16 (plain) or fp32 (FUSE_BN)
    const __hip_bfloat16* __restrict__ BT,  // [Nn,K] row-major (B transposed)
    const float* __restrict__ bias,         // [Nn] or nullptr
    const float* __restrict__ spart,        // [NSLOT][2H] stats partials (FUSE_BN)
    const float* __restrict__ gamma,        // [H] (FUSE_BN)
    const float* __restrict__ beta,         // [H] (FUSE_BN)
    __hip_bfloat16* __restrict__ Cbf,       // [M,Nn]
    int M, int Nn) {
    __shared__ short As[2][64 * 32];    // 8 KB
    __shared__ short Bs[2][128 * 32];   // 16 KB
    __shared__ float scs[H];
    __shared__ float shs[H];
    const short* Ash = (const short*)Ain;
    const float* Af = (const float*)Ain;
    const short* Bsh = (const short*)BT;
    int tid = threadIdx.x;
    int lane = tid & 63;
    int wave = tid >> 6;
    int quad = lane >> 4;
    int lr = lane & 15;
    int wm = (wave & 1) * 32;
    int wn = (wave >> 1) * 64;
    int Mblk = blockIdx.x * 64;
    int Nblk = blockIdx.y * 128;

    f32x4 acc[2][4];
#pragma unroll
    for (int i = 0; i < 2; ++i)
#pragma unroll
        for (int j = 0; j < 4; ++j) acc[i][j] = (f32x4){0.f, 0.f, 0.f, 0.f};

    int srow = tid >> 2, sqs = tid & 3;
    int sqg = sqs ^ ((srow >> 1) & 3);
    int arow = Mblk + srow; if (arow >= M) arow = M - 1;
    int s1 = 256 + tid;
    int brow0 = Nblk + (tid >> 2);
    int qg0 = sqg;
    int brow1 = Nblk + (s1 >> 2);
    int qg1 = (s1 & 3) ^ (((s1 >> 2) >> 1) & 3);

    if (FUSE_BN) {
        int c = tid;
        float s = 0.f, s2 = 0.f;
#pragma unroll 8
        for (int i = 0; i < NSLOT; ++i) {
            s  += spart[(size_t)i * (2 * H) + c];
            s2 += spart[(size_t)i * (2 * H) + H + c];
        }
        float invN = 1.0f / (float)N_NODES;
        float mean = s * invN;
        float var = s2 * invN - mean * mean;
        float kk = gamma[c] / sqrtf(var + EPS_BN);
        scs[c] = kk;
        shs[c] = beta[c] - mean * kk;
        __syncthreads();
    }

    float4 ra0, ra1;
    auto loadA_f = [&](int k0) {
        int kc = k0 + sqg * 8;
        ra0 = *(const float4*)(Af + (size_t)arow * K + kc);
        ra1 = *(const float4*)(Af + (size_t)arow * K + kc + 4);
    };
    auto storeA_f = [&](int buf, int k0) {
        int kc = k0 + sqg * 8;
        float4 c0 = *(const float4*)&scs[kc];
        float4 c1 = *(const float4*)&scs[kc + 4];
        float4 h0 = *(const float4*)&shs[kc];
        float4 h1 = *(const float4*)&shs[kc + 4];
        short8 pk;
        pk[0] = bf16bits(fmaxf(ra0.x * c0.x + h0.x, 0.f));
        pk[1] = bf16bits(fmaxf(ra0.y * c0.y + h0.y, 0.f));
        pk[2] = bf16bits(fmaxf(ra0.z * c0.z + h0.z, 0.f));
        pk[3] = bf16bits(fmaxf(ra0.w * c0.w + h0.w, 0.f));
        pk[4] = bf16bits(fmaxf(ra1.x * c1.x + h1.x, 0.f));
        pk[5] = bf16bits(fmaxf(ra1.y * c1.y + h1.y, 0.f));
        pk[6] = bf16bits(fmaxf(ra1.z * c1.z + h1.z, 0.f));
        pk[7] = bf16bits(fmaxf(ra1.w * c1.w + h1.w, 0.f));
        *(short8*)&As[buf][srow * 32 + sqs * 8] = pk;
    };
    auto stageA_async = [&](int buf, int k0) {
        __builtin_amdgcn_global_load_lds((glob_u32*)(Ash + (size_t)arow * K + k0 + sqg * 8),
                                         (lds_u32*)&As[buf][0] + wave * 256, 16, 0, 0);
    };
    auto stageB = [&](int buf, int k0) {
        __builtin_amdgcn_global_load_lds((glob_u32*)(Bsh + (size_t)brow0 * K + k0 + qg0 * 8),
                                         (lds_u32*)&Bs[buf][0] + wave * 256, 16, 0, 0);
        __builtin_amdgcn_global_load_lds((glob_u32*)(Bsh + (size_t)brow1 * K + k0 + qg1 * 8),
                                         (lds_u32*)&Bs[buf][0] + 1024 + wave * 256, 16, 0, 0);
    };

    constexpr int NK = K / 32;
    if (FUSE_BN) loadA_f(0); else stageA_async(0, 0);
    stageB(0, 0);
#pragma unroll
    for (int k = 0; k < NK; ++k) {
        int buf = k & 1;
        if (FUSE_BN) storeA_f(buf, k * 32);
        __syncthreads();
        if (k + 1 < NK) {
            if (FUSE_BN) loadA_f((k + 1) * 32); else stageA_async(buf ^ 1, (k + 1) * 32);
            stageB(buf ^ 1, (k + 1) * 32);
        }
        short8 af[2], bfr[4];
#pragma unroll
        for (int mi = 0; mi < 2; ++mi) {
            int r = wm + mi * 16 + lr;
            af[mi] = *(const short8*)&As[buf][r * 32 + (quad ^ ((r >> 1) & 3)) * 8];
        }
#pragma unroll
        for (int ni = 0; ni < 4; ++ni) {
            int r = wn + ni * 16 + lr;
            bfr[ni] = *(const short8*)&Bs[buf][r * 32 + (quad ^ ((r >> 1) & 3)) * 8];
        }
#pragma unroll
        for (int mi = 0; mi < 2; ++mi)
#pragma unroll
            for (int ni = 0; ni < 4; ++ni)
                acc[mi][ni] = __builtin_amdgcn_mfma_f32_16x16x32_bf16(af[mi], bfr[ni], acc[mi][ni], 0, 0, 0);
    }
#pragma unroll
    for (int mi = 0; mi < 2; ++mi) {
#pragma unroll
        for (int r = 0; r < 4; ++r) {
            int m = Mblk + wm + mi * 16 + quad * 4 + r;
            if (m < M) {
#pragma unroll
                for (int ni = 0; ni < 4; ++ni) {
                    int n = Nblk + wn + ni * 16 + lr;
                    float v = acc[mi][ni][r];
                    if (bias) v += bias[n];
                    Cbf[(size_t)m * Nn + n] = __float2bfloat16(v);
                }
            }
        }
    }
}

// ---------------- aggregation v3 + fused BN-stats (SETTLED structure) -------------
__global__ __launch_bounds__(256) void agg_kernel(const __hip_bfloat16* __restrict__ t,
                           const int* __restrict__ rowstart,
                           const int* __restrict__ csr_src,
                           const float* __restrict__ csr_w,
                           const float* __restrict__ dinv,
                           const float* __restrict__ convB,
                           float* __restrict__ out,
                           float* __restrict__ spart,  // [NSLOT][2*H]
                           int N) {
    __shared__ float red[2][4][256];  // double-buffered
    int tid = threadIdx.x;
    int wave = tid >> 6;
    int lane = tid & 63;
    int sub = lane >> 5;          // half-wave
    int hl = lane & 31;
    int stream = wave * 2 + sub;  // 0..7
    int c0 = hl * 8;              // gather channel base (8 channels/lane)
    const ushort* tp = (const ushort*)t;
    float sv = 0.f, sq = 0.f;
    int n0 = blockIdx.x * NB;
#pragma unroll 1
    for (int it = 0; it < NB; ++it) {
        int n = n0 + it;
        int s = rowstart[n], e = rowstart[n + 1];
        float a[8] = {};
#pragma unroll 1
        for (int j0 = s; j0 < e; j0 += 16) {
#pragma unroll
            for (int u = 0; u < 2; ++u) {
                int j = j0 + u * 8 + stream;
                int idx = n; float w = 0.f;
                if (j < e) { idx = csr_src[j]; w = csr_w[j]; }
                uint4 v = *(const uint4*)(tp + (size_t)idx * H + c0);
                a[0] += __uint_as_float(v.x << 16) * w;
                a[1] += __uint_as_float(v.x & 0xffff0000u) * w;
                a[2] += __uint_as_float(v.y << 16) * w;
                a[3] += __uint_as_float(v.y & 0xffff0000u) * w;
                a[4] += __uint_as_float(v.z << 16) * w;
                a[5] += __uint_as_float(v.z & 0xffff0000u) * w;
                a[6] += __uint_as_float(v.w << 16) * w;
                a[7] += __uint_as_float(v.w & 0xffff0000u) * w;
            }
        }
#pragma unroll
        for (int k = 0; k < 8; ++k) a[k] += __shfl_xor(a[k], 32);
        int buf = it & 1;
        if (sub == 0) {
            *(float4*)&red[buf][wave][c0] = make_float4(a[0], a[1], a[2], a[3]);
            *(float4*)&red[buf][wave][c0 + 4] = make_float4(a[4], a[5], a[6], a[7]);
        }
        __syncthreads();
        int c = tid;  // channel
        float val = red[buf][0][c] + red[buf][1][c] + red[buf][2][c] + red[buf][3][c];
        float dn = dinv[n];
        val += __bfloat162float(t[(size_t)n * H + c]) * (dn * dn) + convB[c];
        out[(size_t)n * H + c] = val;
        sv += val; sq += val * val;
    }
    float* sp = spart + (size_t)(blockIdx.x & (NSLOT - 1)) * (2 * H);
    atomicAdd(&sp[tid], sv);
    atomicAdd(&sp[H + tid], sq);
}

// ---------------- global mean pool, fused per-block BN params + BN+ReLU ----------
__global__ __launch_bounds__(256) void pool_kernel(const float* __restrict__ t2,
                            const int* __restrict__ batch,
                            const float* __restrict__ spart,
                            const float* __restrict__ gamma,
                            const float* __restrict__ beta,
                            float* __restrict__ g, int N) {
    __shared__ float4 red[4][64];
    __shared__ float scs[H];
    __shared__ float shs[H];
    {
        int c = threadIdx.x;
        float s = 0.f, s2 = 0.f;
#pragma unroll 8
        for (int i = 0; i < NSLOT; ++i) {
            s  += spart[(size_t)i * (2 * H) + c];
            s2 += spart[(size_t)i * (2 * H) + H + c];
        }
        float invN = 1.0f / (float)N_NODES;
        float mean = s * invN;
        float var = s2 * invN - mean * mean;
        float kk = gamma[c] / sqrtf(var + EPS_BN);
        scs[c] = kk;
        shs[c] = beta[c] - mean * kk;
    }
    __syncthreads();
    int gid = blockIdx.x;
    int lo = 0, hi = N;
    while (lo < hi) { int mid = (lo + hi) >> 1; if (batch[mid] < gid) lo = mid + 1; else hi = mid; }
    int s = lo;
    lo = s; hi = N;
    while (lo < hi) { int mid = (lo + hi) >> 1; if (batch[mid] < gid + 1) lo = mid + 1; else hi = mid; }
    int e = lo;
    int wave = threadIdx.x >> 6;
    int lane = threadIdx.x & 63;
    float4 scv = *(const float4*)&scs[lane * 4];
    float4 shv = *(const float4*)&shs[lane * 4];
    float a0 = 0.f, a1 = 0.f, a2 = 0.f, a3 = 0.f;
    for (int r = s + wave; r < e; r += 4) {
        float4 v = *(const float4*)(t2 + (size_t)r * H + lane * 4);
        a0 += __bfloat162float(__float2bfloat16(fmaxf(v.x * scv.x + shv.x, 0.f)));
        a1 += __bfloat162float(__float2bfloat16(fmaxf(v.y * scv.y + shv.y, 0.f)));
        a2 += __bfloat162float(__float2bfloat16(fmaxf(v.z * scv.z + shv.z, 0.f)));
        a3 += __bfloat162float(__float2bfloat16(fmaxf(v.w * scv.w + shv.w, 0.f)));
    }
    red[wave][lane] = make_float4(a0, a1, a2, a3);
    __syncthreads();
    int c = threadIdx.x;
    const float* rf = (const float*)red;
    float sum = rf[c] + rf[256 + c] + rf[512 + c] + rf[768 + c];
    g[(size_t)gid * H + c] = sum / fmaxf((float)(e - s), 1.0f);
}

// ---------------- FC with compile-time K/NN ----------------
template <int K, int NN>
__global__ __launch_bounds__(256) void fc_lds_kernel(const float* __restrict__ in,
                                                     const float* __restrict__ W,
                                                     const float* __restrict__ b,
                                                     float* __restrict__ out) {
    __shared__ float row[K];
    int g = blockIdx.x;
    for (int k = threadIdx.x; k < K; k += 256) row[k] = in[(size_t)g * K + k];
    __syncthreads();
    int hc = threadIdx.x;
    if (hc < NN) {
        float acc = b[hc];
#pragma unroll
        for (int k = 0; k < K; ++k) acc += row[k] * W[k * NN + hc];
        out[(size_t)g * NN + hc] = acc;
    }
}

// ---------------- final FC ----------------
__global__ void fc_out_kernel(const float* __restrict__ in, const float* __restrict__ W,
                              const float* __restrict__ b, float* __restrict__ out) {
    int t = blockIdx.x * blockDim.x + threadIdx.x;
    if (t >= G_GRAPHS * C_OUT) return;
    int g = t / C_OUT, c = t % C_OUT;
    float acc = b[c];
#pragma unroll 16
    for (int k = 0; k < H; ++k) acc += in[(size_t)g * H + k] * W[k * C_OUT + c];
    out[t] = acc;
}

// ---------------- BN over small [G,H] ----------------
__global__ void bn_head_kernel(const float* __restrict__ in, const float* __restrict__ gamma,
                               const float* __restrict__ beta, float* __restrict__ out,
                               int Grows, int relu) {
    int c = blockIdx.x;
    int r = threadIdx.x;
    __shared__ float red[G_GRAPHS];
    float v = in[r * H + c];
    red[r] = v;
    __syncthreads();
    for (int off = G_GRAPHS / 2; off > 0; off >>= 1) {
        if (r < off) red[r] += red[r + off];
        __syncthreads();
    }
    float mean = red[0] / (float)Grows;
    __syncthreads();
    float d = v - mean;
    red[r] = d * d;
    __syncthreads();
    for (int off = G_GRAPHS / 2; off > 0; off >>= 1) {
        if (r < off) red[r] += red[r + off];
        __syncthreads();
    }
    float var = red[0] / (float)Grows;
    float y = gamma[c] * d / sqrtf(var + EPS_BN) + beta[c];
    if (relu) y = fmaxf(y, 0.f);
    out[r * H + c] = y;
}

extern "C" void kernel_launch(void* const* d_in, const int* in_sizes, int n_in,
                              void* d_out, int out_size, void* d_ws, size_t ws_size,
                              hipStream_t stream) {
    const float* x     = (const float*)d_in[0];
    const int*   edge  = (const int*)d_in[1];
    const int*   batch = (const int*)d_in[2];
    const float* encW  = (const float*)d_in[3];
    const float* encB  = (const float*)d_in[4];
    const float* convW = (const float*)d_in[5];
    const float* convB = (const float*)d_in[6];
    const float* bnG   = (const float*)d_in[7];
    const float* bnB   = (const float*)d_in[8];
    const float* fcW1  = (const float*)d_in[9];
    const float* fcB1  = (const float*)d_in[10];
    const float* fcG1  = (const float*)d_in[11];
    const float* fcBe1 = (const float*)d_in[12];
    const float* fcW2  = (const float*)d_in[13];
    const float* fcB2  = (const float*)d_in[14];
    const float* fcG2  = (const float*)d_in[15];
    const float* fcBe2 = (const float*)d_in[16];
    const float* fcW3  = (const float*)d_in[17];
    const float* fcB3  = (const float*)d_in[18];
    float* out = (float*)d_out;

    const int* srcIdx = edge;
    const int* dstIdx = edge + N_EDGES;

    char* base = (char*)d_ws;
    size_t off = 0;
    auto alloc = [&](size_t bytes) -> void* {
        void* p = base + off;
        off = (off + bytes + 255) & ~(size_t)255;
        return p;
    };
    int*   cnt      = (int*)alloc(N_NODES * 4);
    int*   cursor   = (int*)alloc(N_NODES * 4);
    int*   rowstart = (int*)alloc((N_NODES + 1) * 4);
    float* dinv     = (float*)alloc(N_NODES * 4);
    int*   csr_src  = (int*)alloc(N_EDGES * 4);
    float* csr_w    = (float*)alloc(N_EDGES * 4);
    float* spart    = (float*)alloc((size_t)LAYERS * NSLOT * 2 * H * 4);
    __hip_bfloat16* xbf    = (__hip_bfloat16*)alloc((size_t)N_NODES * XDIM * 2);
    __hip_bfloat16* encWT  = (__hip_bfloat16*)alloc((size_t)H * XDIM * 2);
    __hip_bfloat16* convWT = (__hip_bfloat16*)alloc((size_t)LAYERS * H * H * 2);
    __hip_bfloat16* hbf    = (__hip_bfloat16*)alloc((size_t)N_NODES * H * 2);
    __hip_bfloat16* tbf    = (__hip_bfloat16*)alloc((size_t)N_NODES * H * 2);
    float* t2buf = (float*)alloc((size_t)N_NODES * H * 4);
    float* gpool = (float*)alloc(G_GRAPHS * H * 4);
    float* m1    = (float*)alloc(G_GRAPHS * H * 4);
    float* m2    = (float*)alloc(G_GRAPHS * H * 4);

    // cnt+cursor are contiguous in ws -> one memset
    hipMemsetAsync(cnt, 0, (size_t)((char*)rowstart - (char*)cnt), stream);
    hipMemsetAsync(spart, 0, (size_t)LAYERS * NSLOT * 2 * H * 4, stream);

    // CSR build
    hist_kernel<<<(N_EDGES + 255) / 256, 256, 0, stream>>>(dstIdx, cnt, N_EDGES);
    scan_kernel<<<1, 1024, 0, stream>>>(cnt, rowstart, dinv, N_NODES);
    fill_kernel<<<(N_EDGES + 255) / 256, 256, 0, stream>>>(srcIdx, dstIdx, rowstart, cursor,
                                                           dinv, csr_src, csr_w, N_EDGES);

    // fused prep (cast + transposes)
    {
        int total = N_NODES * XDIM + XDIM * H + LAYERS * H * H;
        prep_kernel<<<(total + 255) / 256, 256, 0, stream>>>(x, encW, convW, xbf, encWT, convWT);
    }

    // encoder: h = x @ encW + encB
    dim3 gridG((N_NODES + 63) / 64, H / 128);
    gemm_bf16_kernel<XDIM, false><<<gridG, 256, 0, stream>>>(
        xbf, encWT, encB, nullptr, nullptr, nullptr, hbf, N_NODES, H);

    // conv layers: gemm (BN of prev layer fused into A-staging for l>=1), agg(+stats)
    for (int l = 0; l < LAYERS; ++l) {
        float* spartL = spart + (size_t)l * NSLOT * 2 * H;
        if (l == 0) {
            gemm_bf16_kernel<H, false><<<gridG, 256, 0, stream>>>(
                hbf, convWT + (size_t)l * H * H, nullptr, nullptr, nullptr, nullptr,
                tbf, N_NODES, H);
        } else {
            float* spartP = spart + (size_t)(l - 1) * NSLOT * 2 * H;
            gemm_bf16_kernel<H, true><<<gridG, 256, 0, stream>>>(
                t2buf, convWT + (size_t)l * H * H, nullptr,
                spartP, bnG + (size_t)(l - 1) * H, bnB + (size_t)(l - 1) * H,
                tbf, N_NODES, H);
        }
        agg_kernel<<<N_NODES / NB, 256, 0, stream>>>(tbf, rowstart, csr_src, csr_w, dinv,
                                                     convB + l * H, t2buf, spartL, N_NODES);
    }

    // pool (BN+ReLU of layer 3 fused, params computed per-block)
    pool_kernel<<<G_GRAPHS, 256, 0, stream>>>(
        t2buf, batch, spart + (size_t)(LAYERS - 1) * NSLOT * 2 * H,
        bnG + (size_t)(LAYERS - 1) * H, bnB + (size_t)(LAYERS - 1) * H, gpool, N_NODES);

    // head
    fc_lds_kernel<H, H><<<G_GRAPHS, 256, 0, stream>>>(gpool, fcW1, fcB1, m1);
    bn_head_kernel<<<H, G_GRAPHS, 0, stream>>>(m1, fcG1, fcBe1, m1, G_GRAPHS, 1);
    fc_lds_kernel<H, H><<<G_GRAPHS, 256, 0, stream>>>(m1, fcW2, fcB2, m2);
    bn_head_kernel<<<H, G_GRAPHS, 0, stream>>>(m2, fcG2, fcBe2, m2, G_GRAPHS, 0);
    fc_out_kernel<<<(G_GRAPHS * C_OUT + 255) / 256, 256, 0, stream>>>(m2, fcW3, fcB3, out);
}